// Round 7
// baseline (76.124 us; speedup 1.0000x reference)
//
#include <hip/hip_runtime.h>

// Problem constants (from reference)
constexpr int IN1_C   = 5184;    // 64 bin + 1024 cat + 4096 num
constexpr int BATCH_C = 16384;

typedef float f32x4 __attribute__((ext_vector_type(4)));

__device__ __forceinline__ float dot4(f32x4 a, f32x4 b) {
    return a.x * b.x + a.y * b.y + a.z * b.z + a.w * b.w;
}

// ---------------------------------------------------------------------------
// Weights-in-registers variant. One wave per row; each wave's 64 lanes cover
// all 1296 f32x4 channel-slots (20 full groups + 16-lane remainder), so the
// entire effective weight vector effw[c] = w1[c]*w2[j(c)] lives in 21 f32x4
// VGPRs per lane, and each wave independently computes
//   cst = sum_c b1[c]*w2[j(c)] + sum_j b2[j]
// with a wave-local shuffle reduce. No LDS, no barriers, no second memory
// stream in the hot loop: pure global_load_dwordx4 -> v_fmac on one waitcnt
// domain. (R1/R4/R5/R6 all pinned at ~60us with a dual-stream inner loop.)
// ---------------------------------------------------------------------------
__global__ __launch_bounds__(256) void pwl_reg(
    const float* __restrict__ x,  const float* __restrict__ w1,
    const float* __restrict__ b1, const float* __restrict__ w2,
    const float* __restrict__ b2, float* __restrict__ out)
{
    const int lane = threadIdx.x & 63;
    const int row  = blockIdx.x * 4 + (threadIdx.x >> 6);

    const f32x4* __restrict__ w1v4 = (const f32x4*)w1;
    const f32x4* __restrict__ b1v4 = (const f32x4*)b1;

    // ---- build per-lane weight fragment (84 floats) + bias constant ----
    f32x4 wv[21];                       // fully static-indexed after unroll
    float partial = 0.f;
    #pragma unroll
    for (int k = 0; k < 21; ++k) {
        const int c4 = (k < 20) ? (lane + 64 * k) : ((lane & 15) + 1280);
        const f32x4 a  = w1v4[c4];
        const f32x4 bb = b1v4[c4];
        f32x4 wj;
        #pragma unroll
        for (int e = 0; e < 4; ++e) {
            const int c = 4 * c4 + e;
            int j;
            if (c < 64)        j = c;
            else if (c < 1088) j = 64  + ((c - 64)   >> 4);
            else               j = 128 + ((c - 1088) >> 4);
            wj[e] = w2[j];
        }
        f32x4 ew = a * wj;
        float pb = dot4(bb, wj);
        if (k == 20 && lane >= 16) {    // remainder slots owned by lanes 0..15
            ew.x = 0.f; ew.y = 0.f; ew.z = 0.f; ew.w = 0.f;
            pb = 0.f;
        }
        wv[k] = ew;
        partial += pb;
    }
    #pragma unroll
    for (int i = 0; i < 6; ++i)         // 384 = 64*6 b2 entries
        partial += b2[lane + 64 * i];
    for (int off = 32; off > 0; off >>= 1)
        partial += __shfl_down(partial, off, 64);
    const float cst = __shfl(partial, 0, 64);

    // ---- stream this wave's row: pure HBM read + FMA ----
    const f32x4* __restrict__ xr = (const f32x4*)(x + (size_t)row * IN1_C);

    float s0 = 0.f, s1 = 0.f, s2 = 0.f, s3 = 0.f;
    #pragma unroll
    for (int k = 0; k < 20; k += 4) {
        const int i0 = lane + 64 * k;
        f32x4 a0 = xr[i0];
        f32x4 a1 = xr[i0 + 64];
        f32x4 a2 = xr[i0 + 128];
        f32x4 a3 = xr[i0 + 192];
        s0 += dot4(a0, wv[k]);
        s1 += dot4(a1, wv[k + 1]);
        s2 += dot4(a2, wv[k + 2]);
        s3 += dot4(a3, wv[k + 3]);
    }
    // remainder: all lanes load (lanes>=16 hit lane&15 -> same sectors,
    // coalesced broadcast; their wv[20] is zeroed so contribution is 0)
    {
        f32x4 ar = xr[(lane & 15) + 1280];
        s0 += dot4(ar, wv[20]);
    }

    float sum = (s0 + s1) + (s2 + s3);
    for (int off = 32; off > 0; off >>= 1)
        sum += __shfl_down(sum, off, 64);

    if (lane == 0) out[row] = sum + cst;
}

// ---------------------------------------------------------------------------
extern "C" void kernel_launch(void* const* d_in, const int* in_sizes, int n_in,
                              void* d_out, int out_size, void* d_ws, size_t ws_size,
                              hipStream_t stream)
{
    const float* x  = (const float*)d_in[0];   // (16384, 5184, 1) f32
    const float* w1 = (const float*)d_in[1];   // (5184,)
    const float* b1 = (const float*)d_in[2];   // (5184,)
    const float* w2 = (const float*)d_in[3];   // (384,)
    const float* b2 = (const float*)d_in[4];   // (384,)
    float* out = (float*)d_out;                // (16384,)

    const int blocks = BATCH_C / 4;            // 1 row per wave, 4 waves/block
    pwl_reg<<<blocks, 256, 0, stream>>>(x, w1, b1, w2, b2, out);
}

// Round 8
// 68.600 us; speedup vs baseline: 1.1097x; 1.1097x over previous
//
#include <hip/hip_runtime.h>

// Problem constants (from reference)
constexpr int NUM_BIN  = 64;
constexpr int NUM_CAT  = 1024;   // 64 groups x 16
constexpr int NUM_NUM  = 4096;   // 256 groups x 16
constexpr int IN1_C    = NUM_BIN + NUM_CAT + NUM_NUM;   // 5184
constexpr int IN2_C    = 64 + 64 + 256;                 // 384
constexpr int BATCH_C  = 16384;
constexpr int NF4      = IN1_C / 4;                     // 1296 float4 per row

constexpr int NBLK     = 1024;           // 4 blocks/CU -> ALL blocks co-resident
constexpr int NWAVE    = NBLK * 4;       // 4096 waves
constexpr int ROWS_PW  = BATCH_C / NWAVE; // 4 rows per wave

typedef float f32x4 __attribute__((ext_vector_type(4)));

__device__ __forceinline__ float dot4(f32x4 a, f32x4 b) {
    return a.x * b.x + a.y * b.y + a.z * b.z + a.w * b.w;
}

// ---------------------------------------------------------------------------
// R6 base (resident grid, one-time LDS weights) + TWO-ROW INTERLEAVE:
// each wave streams rows (r, r+NWAVE) together with 8 independent
// accumulators and 8 loads in flight per step, eliminating the per-row
// drain bubble (reduce+store with zero loads outstanding) that R6 paid
// 4x per wave.
// ---------------------------------------------------------------------------
__global__ __launch_bounds__(256) void pwl_fused(
    const float* __restrict__ x,  const float* __restrict__ w1,
    const float* __restrict__ b1, const float* __restrict__ w2,
    const float* __restrict__ b2, float* __restrict__ out)
{
    __shared__ f32x4 wlds[NF4];          // 20.7 KB
    __shared__ float red[4];

    const int tid  = threadIdx.x;
    const int lane = tid & 63;
    const int wid  = tid >> 6;
    const int gwave = blockIdx.x * 4 + wid;

    float* wl = (float*)wlds;

    // ---- stage effw into LDS + accumulate bias constant (once per block) ----
    float partial = 0.f;
    #pragma unroll
    for (int i = 0; i < 20; ++i) {
        const int c = tid + 256 * i;
        int j;
        if (c < NUM_BIN)                j = c;
        else if (c < NUM_BIN + NUM_CAT) j = NUM_BIN + ((c - NUM_BIN) >> 4);
        else                            j = 128 + ((c - NUM_BIN - NUM_CAT) >> 4);
        const float w2j = w2[j];
        wl[c]    = w1[c] * w2j;
        partial += b1[c] * w2j;
    }
    if (tid < 64) {                      // channels 5120..5183 (all in num range)
        const int c = 5120 + tid;
        const float w2j = w2[128 + ((c - NUM_BIN - NUM_CAT) >> 4)];
        wl[c]    = w1[c] * w2j;
        partial += b1[c] * w2j;
    }
    partial += b2[tid] + ((tid < IN2_C - 256) ? b2[tid + 256] : 0.f);

    for (int off = 32; off > 0; off >>= 1)
        partial += __shfl_down(partial, off, 64);
    if (lane == 0) red[wid] = partial;
    __syncthreads();                     // covers wlds and red

    const float cst = (red[0] + red[1]) + (red[2] + red[3]);

    // ---- stream rows two-at-a-time ----
    #pragma unroll
    for (int rp = 0; rp < ROWS_PW; rp += 2) {
        const int rowA = gwave + rp * NWAVE;
        const int rowB = rowA + NWAVE;
        const f32x4* __restrict__ xa = (const f32x4*)(x + (size_t)rowA * IN1_C);
        const f32x4* __restrict__ xb = (const f32x4*)(x + (size_t)rowB * IN1_C);

        float a0 = 0.f, a1 = 0.f, a2 = 0.f, a3 = 0.f;
        float c0 = 0.f, c1 = 0.f, c2 = 0.f, c3 = 0.f;
        #pragma unroll
        for (int k = 0; k < 20; k += 4) {
            const int i0 = lane + 64 * k;
            f32x4 va0 = xa[i0];
            f32x4 va1 = xa[i0 + 64];
            f32x4 va2 = xa[i0 + 128];
            f32x4 va3 = xa[i0 + 192];
            f32x4 vb0 = xb[i0];
            f32x4 vb1 = xb[i0 + 64];
            f32x4 vb2 = xb[i0 + 128];
            f32x4 vb3 = xb[i0 + 192];
            f32x4 w0 = wlds[i0];
            f32x4 w1v = wlds[i0 + 64];
            f32x4 w2v = wlds[i0 + 128];
            f32x4 w3v = wlds[i0 + 192];
            a0 += dot4(va0, w0);
            a1 += dot4(va1, w1v);
            a2 += dot4(va2, w2v);
            a3 += dot4(va3, w3v);
            c0 += dot4(vb0, w0);
            c1 += dot4(vb1, w1v);
            c2 += dot4(vb2, w2v);
            c3 += dot4(vb3, w3v);
        }
        // remainder: 1296 - 1280 = 16 float4
        if (lane < 16) {
            f32x4 va = xa[lane + 1280];
            f32x4 vb = xb[lane + 1280];
            f32x4 w  = wlds[lane + 1280];
            a0 += dot4(va, w);
            c0 += dot4(vb, w);
        }

        float sumA = (a0 + a1) + (a2 + a3);
        float sumB = (c0 + c1) + (c2 + c3);
        for (int off = 32; off > 0; off >>= 1) {
            sumA += __shfl_down(sumA, off, 64);
            sumB += __shfl_down(sumB, off, 64);
        }
        if (lane == 0) {
            out[rowA] = sumA + cst;
            out[rowB] = sumB + cst;
        }
    }
}

// ---------------------------------------------------------------------------
extern "C" void kernel_launch(void* const* d_in, const int* in_sizes, int n_in,
                              void* d_out, int out_size, void* d_ws, size_t ws_size,
                              hipStream_t stream)
{
    const float* x  = (const float*)d_in[0];   // (16384, 5184, 1) f32
    const float* w1 = (const float*)d_in[1];   // (5184,)
    const float* b1 = (const float*)d_in[2];   // (5184,)
    const float* w2 = (const float*)d_in[3];   // (384,)
    const float* b2 = (const float*)d_in[4];   // (384,)
    float* out = (float*)d_out;                // (16384,)

    pwl_fused<<<NBLK, 256, 0, stream>>>(x, w1, b1, w2, b2, out);
}

// Round 9
// 54.080 us; speedup vs baseline: 1.4076x; 1.2685x over previous
//
#include <hip/hip_runtime.h>

// Problem constants (from reference)
constexpr int NUM_BIN  = 64;
constexpr int NUM_CAT  = 1024;   // 64 groups x 16
constexpr int NUM_NUM  = 4096;   // 256 groups x 16
constexpr int IN1_C    = NUM_BIN + NUM_CAT + NUM_NUM;   // 5184
constexpr int IN2_C    = 64 + 64 + 256;                 // 384
constexpr int BATCH_C  = 16384;
constexpr int NF4      = IN1_C / 4;                     // 1296 float4 per row

constexpr int NBLK     = 1024;           // 4 blocks/CU -> ALL blocks co-resident
constexpr int NWAVE    = NBLK * 4;       // 4096 waves
constexpr int ROWS_PW  = BATCH_C / NWAVE; // 4 rows per wave

typedef float f32x4 __attribute__((ext_vector_type(4)));

__device__ __forceinline__ float dot4(f32x4 a, f32x4 b) {
    return a.x * b.x + a.y * b.y + a.z * b.z + a.w * b.w;
}

// ---------------------------------------------------------------------------
// R6 structure (best: 60.5us), single change: x loads are NONTEMPORAL.
// x is a 340MB one-pass stream; default loads allocate every line in L1/L2
// (4MB/XCD -> pure thrash). nt marks lines evict-first, the only remaining
// mechanism for the 5.6 vs 6.3-6.9 TB/s read-vs-write BW gap.
// ---------------------------------------------------------------------------
__global__ __launch_bounds__(256) void pwl_fused(
    const float* __restrict__ x,  const float* __restrict__ w1,
    const float* __restrict__ b1, const float* __restrict__ w2,
    const float* __restrict__ b2, float* __restrict__ out)
{
    __shared__ f32x4 wlds[NF4];          // 20.7 KB
    __shared__ float red[4];

    const int tid  = threadIdx.x;
    const int lane = tid & 63;
    const int wid  = tid >> 6;
    const int gwave = blockIdx.x * 4 + wid;

    float* wl = (float*)wlds;

    // ---- stage effw into LDS + accumulate bias constant (once per block) ----
    float partial = 0.f;
    #pragma unroll
    for (int i = 0; i < 20; ++i) {
        const int c = tid + 256 * i;
        int j;
        if (c < NUM_BIN)                j = c;
        else if (c < NUM_BIN + NUM_CAT) j = NUM_BIN + ((c - NUM_BIN) >> 4);
        else                            j = 128 + ((c - NUM_BIN - NUM_CAT) >> 4);
        const float w2j = w2[j];
        wl[c]    = w1[c] * w2j;
        partial += b1[c] * w2j;
    }
    if (tid < 64) {                      // channels 5120..5183 (all in num range)
        const int c = 5120 + tid;
        const float w2j = w2[128 + ((c - NUM_BIN - NUM_CAT) >> 4)];
        wl[c]    = w1[c] * w2j;
        partial += b1[c] * w2j;
    }
    partial += b2[tid] + ((tid < IN2_C - 256) ? b2[tid + 256] : 0.f);

    for (int off = 32; off > 0; off >>= 1)
        partial += __shfl_down(partial, off, 64);
    if (lane == 0) red[wid] = partial;
    __syncthreads();                     // covers wlds and red

    const float cst = (red[0] + red[1]) + (red[2] + red[3]);

    // ---- stream ROWS_PW rows per wave (nontemporal x reads) ----
    #pragma unroll
    for (int rr = 0; rr < ROWS_PW; ++rr) {
        const int row = gwave + rr * NWAVE;
        const f32x4* __restrict__ xr = (const f32x4*)(x + (size_t)row * IN1_C);

        float s0 = 0.f, s1 = 0.f, s2 = 0.f, s3 = 0.f;
        #pragma unroll
        for (int k = 0; k < 20; k += 4) {
            const int i0 = lane + 64 * k;
            f32x4 a0 = __builtin_nontemporal_load(&xr[i0]);
            f32x4 a1 = __builtin_nontemporal_load(&xr[i0 + 64]);
            f32x4 a2 = __builtin_nontemporal_load(&xr[i0 + 128]);
            f32x4 a3 = __builtin_nontemporal_load(&xr[i0 + 192]);
            f32x4 w0 = wlds[i0];
            f32x4 w1v = wlds[i0 + 64];
            f32x4 w2v = wlds[i0 + 128];
            f32x4 w3v = wlds[i0 + 192];
            s0 += dot4(a0, w0);
            s1 += dot4(a1, w1v);
            s2 += dot4(a2, w2v);
            s3 += dot4(a3, w3v);
        }
        // remainder: 1296 - 1280 = 16 float4
        if (lane < 16) {
            f32x4 a = __builtin_nontemporal_load(&xr[lane + 1280]);
            f32x4 w = wlds[lane + 1280];
            s0 += dot4(a, w);
        }

        float sum = (s0 + s1) + (s2 + s3);
        for (int off = 32; off > 0; off >>= 1)
            sum += __shfl_down(sum, off, 64);

        if (lane == 0) out[row] = sum + cst;
    }
}

// ---------------------------------------------------------------------------
extern "C" void kernel_launch(void* const* d_in, const int* in_sizes, int n_in,
                              void* d_out, int out_size, void* d_ws, size_t ws_size,
                              hipStream_t stream)
{
    const float* x  = (const float*)d_in[0];   // (16384, 5184, 1) f32
    const float* w1 = (const float*)d_in[1];   // (5184,)
    const float* b1 = (const float*)d_in[2];   // (5184,)
    const float* w2 = (const float*)d_in[3];   // (384,)
    const float* b2 = (const float*)d_in[4];   // (384,)
    float* out = (float*)d_out;                // (16384,)

    pwl_fused<<<NBLK, 256, 0, stream>>>(x, w1, b1, w2, b2, out);
}